// Round 4
// baseline (128.606 us; speedup 1.0000x reference)
//
#include <hip/hip_runtime.h>

// ---------------------------------------------------------------------------
// Stacked 3-layer LSTM step + projection, B=256, I=512, H=1024, V=512 (fp32 io)
// bf16 MFMA GEMMs. Key structure (round 4):
//   - A (bf16 activations) read per-wave DIRECTLY from global as MFMA frags
//     (L2-resident; no LDS staging, no barrier dependency for A).
//   - W (fp32) streamed -> converted -> transposed into tiny LDS (2 x 4 KB
//     double buffer), depth-3 register prefetch across raw s_barriers
//     (counted vmcnt survives; __syncthreads would drain it).
//   - BM=128 x BN=32 x K-split-2 -> grid 512 = 2 blocks/CU, 512 thr,
//     wave tile 32x16, VGPR<=128 (__launch_bounds__(512,4)).
// ---------------------------------------------------------------------------

typedef __attribute__((ext_vector_type(8))) short short8_t;            // 8 bf16 (MFMA frag)
typedef __attribute__((ext_vector_type(4))) unsigned short ushort4_t;  // 8B st
typedef __attribute__((ext_vector_type(4))) float f32x4;               // MFMA acc / 16B ld

__device__ __forceinline__ unsigned short f2bf(float f) {
    union { float f; unsigned u; } v; v.f = f;
    unsigned r = v.u + 0x7FFFu + ((v.u >> 16) & 1u);   // RTNE (finite inputs)
    return (unsigned short)(r >> 16);
}

#define KT 64
#define BN 32

// ---------------------------------------------------------------------------
// zp[kb][256][N] = A[256][K-slice kb] @ W[K-slice kb][N]
// A = concat(A1[256][K1], A2[256][Ktot-K1]) bf16; W rows fp32 -> bf16 in reg.
// grid = 2(m-half) * (N/32) * nsplit ; block 512 thr = 8 waves.
// wave w: mg=w>>1 (rows mh*128+mg*32..+32), ng=w&1 (cols n0+ng*16..+16).
// ---------------------------------------------------------------------------
__global__ __launch_bounds__(512, 4)
void gemm_ar(const unsigned short* __restrict__ A1, const float* __restrict__ W1, int K1,
             const unsigned short* __restrict__ A2, const float* __restrict__ W2,
             int N, int Ktot, int lgs, int nstrips, float* __restrict__ zp)
{
    __shared__ unsigned short Wl0[BN * KT];    // 4 KB, [n][k] transposed, swizzled
    __shared__ unsigned short Wl1[BN * KT];    // 4 KB

    const int tid  = threadIdx.x;
    const int lane = tid & 63;
    const int w    = tid >> 6;
    const int mg   = w >> 1;
    const int ng   = w & 1;
    const int lg   = lane >> 4;
    const int lr   = lane & 15;

    const int nsplit = 1 << lgs;
    const int kb   = blockIdx.x & (nsplit - 1);
    const int rest = blockIdx.x >> lgs;
    const int ns   = rest % nstrips;
    const int mh   = rest / nstrips;

    const int n0   = ns * BN;
    const int m0   = mh * 128 + mg * 32;
    const int klen = Ktot >> lgs;
    const int kbeg = kb * klen;
    const int nt   = klen >> 6;

    const int wr = tid >> 3;               // W k-row within tile (0..63)
    const int wq = tid & 7;                // W col-quad (0..7) -> cols wq*4..+4

    // prefetch register sets (all statically named - rule #20)
    short8_t a0[4], a1[4], a2[4];          // A frags: (ks0,r0),(ks0,r1),(ks1,r0),(ks1,r1)
    f32x4    w0, w1, w2;                   // W row-chunks

    f32x4 acc0 = {0.f,0.f,0.f,0.f}, acc1 = {0.f,0.f,0.f,0.f};

    auto issueA = [&](int t, short8_t (&a)[4]) {
        int k0 = kbeg + t * KT;
        const unsigned short* A; int ldA, krel;
        if (k0 < K1) { A = A1; ldA = K1;        krel = k0; }
        else         { A = A2; ldA = Ktot - K1; krel = k0 - K1; }
        const unsigned short* base = A + (size_t)(m0 + lr) * ldA + krel + lg * 8;
        a[0] = *(const short8_t*)(base);
        a[1] = *(const short8_t*)(base + (size_t)16 * ldA);
        a[2] = *(const short8_t*)(base + 32);
        a[3] = *(const short8_t*)(base + (size_t)16 * ldA + 32);
    };

    auto issueW = [&](int t, f32x4& wv) {
        int k0 = kbeg + t * KT;
        const float* Wm; int krel;
        if (k0 < K1) { Wm = W1; krel = k0; }
        else         { Wm = W2; krel = k0 - K1; }
        wv = *(const f32x4*)(Wm + (size_t)(krel + wr) * N + n0 + wq * 4);
    };

    auto stageW = [&](const f32x4& wv, unsigned short* wl) {
        int kch = wr >> 3, kwi = wr & 7;
#pragma unroll
        for (int j = 0; j < 4; ++j) {
            int n = wq * 4 + j;            // transposed: Wl[n][k], 16B-chunk XOR swizzle
            wl[n * KT + ((kch ^ (n & 7)) << 3) + kwi] = f2bf(wv[j]);
        }
    };

    auto compute = [&](const unsigned short* wl, short8_t (&a)[4]) {
#pragma unroll
        for (int ks = 0; ks < 2; ++ks) {
            int ch = ks * 4 + lg;
            int nb = ng * 16 + lr;
            short8_t b = *(const short8_t*)(wl + nb * KT + ((ch ^ (nb & 7)) << 3));
            acc0 = __builtin_amdgcn_mfma_f32_16x16x32_bf16(a[ks * 2],     b, acc0, 0, 0, 0);
            acc1 = __builtin_amdgcn_mfma_f32_16x16x32_bf16(a[ks * 2 + 1], b, acc1, 0, 0, 0);
        }
    };

#define BAR() do { asm volatile("s_waitcnt lgkmcnt(0)" ::: "memory"); \
                   __builtin_amdgcn_s_barrier(); } while (0)

    // prologue: W depth-3, A depth-2, tile 0 staged
    issueW(0, w0);
    if (1 < nt) issueW(1, w1);
    issueA(0, a0);
    stageW(w0, Wl0);
    if (2 < nt) issueW(2, w2);
    if (1 < nt) issueA(1, a1);
    BAR();                                 // Wl0 (tile 0) published

    // phase p: stage w[(p+1)%3]->Wl[(p+1)&1]; issueW(p+3)->w[(p+3)%3];
    //          issueA(p+2)->a[(p+2)%3]; compute(Wl[p&1], a[p%3]); barrier.
#define PHASE(p, WST, WLST, WIS, AIS, WLC, ACM) \
    if ((p) < nt) { \
        if ((p) + 1 < nt) stageW(WST, WLST); \
        if ((p) + 3 < nt) issueW((p) + 3, WIS); \
        if ((p) + 2 < nt) issueA((p) + 2, AIS); \
        compute(WLC, ACM); \
        BAR(); \
    }

    for (int t = 0; t < nt; t += 6) {
        PHASE(t + 0, w1, Wl1, w0, a2, Wl0, a0)
        PHASE(t + 1, w2, Wl0, w1, a0, Wl1, a1)
        PHASE(t + 2, w0, Wl1, w2, a1, Wl0, a2)
        PHASE(t + 3, w1, Wl0, w0, a2, Wl1, a0)
        PHASE(t + 4, w2, Wl1, w1, a0, Wl0, a1)
        PHASE(t + 5, w0, Wl0, w2, a1, Wl1, a2)
    }
#undef PHASE
#undef BAR

    // epilogue: D mapping col=lane&15, row=4*(lane>>4)+reg  [m89/m91]
    float* zq = zp + (size_t)kb * 256 * N;
    const int nc = n0 + ng * 16 + lr;
#pragma unroll
    for (int r = 0; r < 4; ++r) {
        zq[(size_t)(m0 + lg * 4 + r) * N + nc]      = acc0[r];
        zq[(size_t)(m0 + 16 + lg * 4 + r) * N + nc] = acc1[r];
    }
}

// ---------------------------------------------------------------------------
// Gates: z = sum_kb zp[kb] + bias -> h_new, c_new (fp32) + h_new bf16
// ---------------------------------------------------------------------------
__global__ __launch_bounds__(256)
void lstm_gates(const float* __restrict__ zp, int nsplit,
                const float* __restrict__ bias, const float* __restrict__ c_old,
                float* __restrict__ h_out, float* __restrict__ c_out,
                unsigned short* __restrict__ h_bf)
{
    int t = blockIdx.x * 256 + threadIdx.x;   // 65536 threads, 4 elems each
    int b = t >> 8;
    int n = (t & 255) << 2;
    f32x4 iv = *(const f32x4*)(bias + n);
    f32x4 fv = *(const f32x4*)(bias + 1024 + n);
    f32x4 gv = *(const f32x4*)(bias + 2048 + n);
    f32x4 ov = *(const f32x4*)(bias + 3072 + n);
    for (int kb = 0; kb < nsplit; ++kb) {
        const float* z = zp + (size_t)kb * 1048576 + (size_t)b * 4096;
        iv += *(const f32x4*)(z + n);
        fv += *(const f32x4*)(z + 1024 + n);
        gv += *(const f32x4*)(z + 2048 + n);
        ov += *(const f32x4*)(z + 3072 + n);
    }
    f32x4 cv = *(const f32x4*)(c_old + (size_t)b * 1024 + n);

    f32x4 hn, cn;
    ushort4_t hb;
#pragma unroll
    for (int j = 0; j < 4; ++j) {
        float ii = 1.f / (1.f + __expf(-iv[j]));
        float ff = 1.f / (1.f + __expf(-fv[j]));
        float gg = tanhf(gv[j]);
        float oo = 1.f / (1.f + __expf(-ov[j]));
        float c2 = ff * cv[j] + ii * gg;
        cn[j] = c2;
        float h2 = oo * tanhf(c2);
        hn[j] = h2;
        hb[j] = f2bf(h2);
    }
    *(f32x4*)(c_out + (size_t)b * 1024 + n) = cn;
    *(f32x4*)(h_out + (size_t)b * 1024 + n) = hn;
    *(ushort4_t*)(h_bf + (size_t)b * 1024 + n) = hb;
}

// ---------------------------------------------------------------------------
// logits = sum_kb zp[kb] + bp   (proj partial reduce), N=512
// ---------------------------------------------------------------------------
__global__ __launch_bounds__(256)
void finalize_proj(const float* __restrict__ zp, int nsplit,
                   const float* __restrict__ bp, float* __restrict__ logits)
{
    int t = blockIdx.x * 256 + threadIdx.x;   // 32768 threads x 4 elems
    int i = t * 4;
    f32x4 v = *(const f32x4*)(bp + (i & 511));
    for (int kb = 0; kb < nsplit; ++kb)
        v += *(const f32x4*)(zp + (size_t)kb * 131072 + i);
    *(f32x4*)(logits + i) = v;
}

// ---------------------------------------------------------------------------
// Pack fp32 -> bf16 for x, h0, h1, h2
// ---------------------------------------------------------------------------
__global__ __launch_bounds__(256)
void pack_bf16(const float* __restrict__ x,  const float* __restrict__ h0,
               const float* __restrict__ h1, const float* __restrict__ h2,
               unsigned short* __restrict__ xb,  unsigned short* __restrict__ h0b,
               unsigned short* __restrict__ h1b, unsigned short* __restrict__ h2b)
{
    int t = blockIdx.x * 256 + threadIdx.x;
    const float* src; unsigned short* dst; int off;
    if (t < 32768)       { src = x;  dst = xb;  off = t; }
    else if (t < 98304)  { src = h0; dst = h0b; off = t - 32768; }
    else if (t < 163840) { src = h1; dst = h1b; off = t - 98304; }
    else                 { src = h2; dst = h2b; off = t - 163840; }
    f32x4 v = *(const f32x4*)(src + (size_t)off * 4);
    ushort4_t o;
#pragma unroll
    for (int j = 0; j < 4; ++j) o[j] = f2bf(v[j]);
    *(ushort4_t*)(dst + (size_t)off * 4) = o;
}

// ---------------------------------------------------------------------------
extern "C" void kernel_launch(void* const* d_in, const int* in_sizes, int n_in,
                              void* d_out, int out_size, void* d_ws, size_t ws_size,
                              hipStream_t stream)
{
    const float* x  = (const float*)d_in[0];
    const float* h0 = (const float*)d_in[1];
    const float* c0 = (const float*)d_in[2];
    const float* h1 = (const float*)d_in[3];
    const float* c1 = (const float*)d_in[4];
    const float* h2 = (const float*)d_in[5];
    const float* c2 = (const float*)d_in[6];
    const float* W0 = (const float*)d_in[7];
    const float* U0 = (const float*)d_in[8];
    const float* b0 = (const float*)d_in[9];
    const float* W1 = (const float*)d_in[10];
    const float* U1 = (const float*)d_in[11];
    const float* b1 = (const float*)d_in[12];
    const float* W2 = (const float*)d_in[13];
    const float* U2 = (const float*)d_in[14];
    const float* b2 = (const float*)d_in[15];
    const float* Wp = (const float*)d_in[16];
    const float* bp = (const float*)d_in[17];

    float* out    = (float*)d_out;
    float* logits = out;                    // [256,512]
    float* h0n = out + 131072;              // [256,1024] each below
    float* c0n = h0n + 262144;
    float* h1n = c0n + 262144;
    float* c1n = h1n + 262144;
    float* h2n = c1n + 262144;
    float* c2n = h2n + 262144;

    // nsplit=2 needs: zp 8MB + xb 256KB + 6x h-bf16 512KB = 11,796,480 B
    const size_t need2 = 8388608ull + 262144ull + 6ull * 524288ull;
    const int nsplit = (ws_size >= need2) ? 2 : 1;
    const int lgs    = (nsplit == 2) ? 1 : 0;
    const size_t zbytes = (size_t)nsplit * 4194304ull;

    char* ws = (char*)d_ws;
    float*          zp   = (float*)ws;                         // [nsplit][256][4096]
    unsigned short* xb   = (unsigned short*)(ws + zbytes);
    unsigned short* h0b  = (unsigned short*)(ws + zbytes + 262144);
    unsigned short* h1b  = (unsigned short*)(ws + zbytes + 262144 + 524288);
    unsigned short* h2b  = (unsigned short*)(ws + zbytes + 262144 + 2*524288);
    unsigned short* h0nb = (unsigned short*)(ws + zbytes + 262144 + 3*524288);
    unsigned short* h1nb = (unsigned short*)(ws + zbytes + 262144 + 4*524288);
    unsigned short* h2nb = (unsigned short*)(ws + zbytes + 262144 + 5*524288);

    pack_bf16<<<896, 256, 0, stream>>>(x, h0, h1, h2, xb, h0b, h1b, h2b);

    // layer 0: z = x@W0 + h0@U0   (K1=512, Ktot=1536)
    gemm_ar<<<2 * 128 * nsplit, 512, 0, stream>>>(xb, W0, 512, h0b, U0, 4096, 1536, lgs, 128, zp);
    lstm_gates<<<256, 256, 0, stream>>>(zp, nsplit, b0, c0, h0n, c0n, h0nb);

    // layer 1: z = h0n@W1 + h1@U1  (K1=1024, Ktot=2048)
    gemm_ar<<<2 * 128 * nsplit, 512, 0, stream>>>(h0nb, W1, 1024, h1b, U1, 4096, 2048, lgs, 128, zp);
    lstm_gates<<<256, 256, 0, stream>>>(zp, nsplit, b1, c1, h1n, c1n, h1nb);

    // layer 2: z = h1n@W2 + h2@U2  (K1=1024, Ktot=2048)
    gemm_ar<<<2 * 128 * nsplit, 512, 0, stream>>>(h1nb, W2, 1024, h2b, U2, 4096, 2048, lgs, 128, zp);
    lstm_gates<<<256, 256, 0, stream>>>(zp, nsplit, b2, c2, h2n, c2n, h2nb);

    // projection: logits = h2n@Wp + bp  (K=1024, N=512)
    gemm_ar<<<2 * 16 * nsplit, 512, 0, stream>>>(h2nb, Wp, 1024,
                                                 (const unsigned short*)nullptr,
                                                 (const float*)nullptr, 512, 1024, lgs, 16, zp);
    finalize_proj<<<128, 256, 0, stream>>>(zp, nsplit, bp, logits);
}

// Round 5
// 78.119 us; speedup vs baseline: 1.6463x; 1.6463x over previous
//
#include <hip/hip_runtime.h>

// ---------------------------------------------------------------------------
// Stacked 3-layer LSTM step + projection, B=256, I=512, H=1024, V=512 (fp32 io)
// Round 5: dependency-graph restructure.
//   Phase 1 (mega, 1 launch, 512 blocks): x@W0, h0@U0, h1@U1, h2@U2 (56 MB of
//     weights — all available at t=0).
//   Serial tail: gates0 -> h0n@W1 -> gates1 -> h1n@W2 -> gates2 -> h2n@Wp.
// GEMM body = round-2 proven structure (BM=256, BN=32, LDS dbuf, ping-pong
// prefetch), now at 2 blocks/CU (launch_bounds(512,4), 72 KB LDS).
// ---------------------------------------------------------------------------

typedef __attribute__((ext_vector_type(8))) short short8_t;            // 8 bf16 (MFMA frag)
typedef __attribute__((ext_vector_type(8))) unsigned short ushort8_t;  // 16B ld/st
typedef __attribute__((ext_vector_type(4))) unsigned short ushort4_t;  // 8B st
typedef __attribute__((ext_vector_type(4))) float f32x4;               // MFMA acc / 16B ld

__device__ __forceinline__ unsigned short f2bf(float f) {
    union { float f; unsigned u; } v; v.f = f;
    unsigned r = v.u + 0x7FFFu + ((v.u >> 16) & 1u);   // RTNE (finite inputs)
    return (unsigned short)(r >> 16);
}

#define KT 64
#define BN 32

struct GemmPiece {
    const unsigned short* A;   // [256][K] bf16 bits
    const float*          W;   // [K][N] fp32
    float*                Z;   // partials: [1<<lgs][256][N]
    int K;
    int lgs;                   // K-split log2
    int bstart;                // first block id of this piece
};
struct GemmDesc { GemmPiece p[4]; int np; int N; };

// ---------------------------------------------------------------------------
// Z[kb][256][N] = A[256][K-slice kb] @ W[K-slice kb][N]   (per piece)
// Block: 512 thr (8 waves), BM=256, BN=32 cols. Wave w: rows w*32..+32,
// 2x2 16x16 MFMA tiles. LDS double-buffer, ping-pong register prefetch.
// ---------------------------------------------------------------------------
__global__ __launch_bounds__(512, 4)
void gemm_multi(GemmDesc d)
{
    __shared__ unsigned short Al0[256 * KT];   // 32 KB, 16B-chunk XOR swizzled
    __shared__ unsigned short Al1[256 * KT];   // 32 KB
    __shared__ unsigned short Wl0[BN * KT];    // 4 KB, [n][k] transposed, swizzled
    __shared__ unsigned short Wl1[BN * KT];    // 4 KB

    const int bid = blockIdx.x;
    int pi = 0;
#pragma unroll
    for (int i = 1; i < 4; ++i)
        if (i < d.np && bid >= d.p[i].bstart) pi = i;
    const unsigned short* __restrict__ A = d.p[pi].A;
    const float* __restrict__ W = d.p[pi].W;
    const int K   = d.p[pi].K;
    const int lgs = d.p[pi].lgs;
    const int N   = d.N;
    const int lb  = bid - d.p[pi].bstart;
    const int nsplit = 1 << lgs;
    const int kb  = lb & (nsplit - 1);
    const int ns  = lb >> lgs;

    const int tid  = threadIdx.x;
    const int lane = tid & 63;
    const int w    = tid >> 6;
    const int lg   = lane >> 4;
    const int lr   = lane & 15;
    const int n0   = ns * BN;
    const int m0   = w * 32;
    const int klen = K >> lgs;
    const int kbeg = kb * klen;
    const int nt   = klen >> 6;            // 4, 8, or 16 (always even)

    const int wkr = tid >> 3;              // W k-row within tile 0..63
    const int wcq = tid & 7;               // W float4-col 0..7

    ushort8_t paA[4], paB[4];              // ping-pong A prefetch (static idx)
    f32x4     pwA,   pwB;                  // ping-pong W prefetch

    f32x4 acc00 = {0,0,0,0}, acc01 = {0,0,0,0}, acc10 = {0,0,0,0}, acc11 = {0,0,0,0};

    auto issue = [&](int t, ushort8_t (&pa)[4], f32x4& pw) {
        int k0 = kbeg + t * KT;
#pragma unroll
        for (int it = 0; it < 4; ++it) {
            int c = tid + it * 512;        // 2048 chunks = 256 rows x 8
            int row = c >> 3, cc = c & 7;
            pa[it] = *(const ushort8_t*)(A + (size_t)row * K + k0 + cc * 8);
        }
        pw = *(const f32x4*)(W + (size_t)(k0 + wkr) * N + n0 + wcq * 4);
    };

    auto stage = [&](ushort8_t (&pa)[4], f32x4& pw,
                     unsigned short* al, unsigned short* wl) {
#pragma unroll
        for (int it = 0; it < 4; ++it) {
            int c = tid + it * 512;
            int row = c >> 3, cc = c & 7;
            *(ushort8_t*)(al + row * KT + ((cc ^ (row & 7)) << 3)) = pa[it];
        }
        unsigned short bs[4] = { f2bf(pw[0]), f2bf(pw[1]), f2bf(pw[2]), f2bf(pw[3]) };
        int kch = wkr >> 3, kwi = wkr & 7;
#pragma unroll
        for (int j = 0; j < 4; ++j) {
            int n = wcq * 4 + j;           // transposed: Wl[n][k]
            wl[n * KT + ((kch ^ (n & 7)) << 3) + kwi] = bs[j];
        }
    };

    auto compute = [&](const unsigned short* al, const unsigned short* wl) {
#pragma unroll
        for (int ks = 0; ks < 2; ++ks) {
            int ch = ks * 4 + lg;
            int nb0 = lr, nb1 = 16 + lr;
            short8_t b0f = *(const short8_t*)(wl + nb0 * KT + ((ch ^ (nb0 & 7)) << 3));
            short8_t b1f = *(const short8_t*)(wl + nb1 * KT + ((ch ^ (nb1 & 7)) << 3));
            int r0 = m0 + lr, r1 = m0 + 16 + lr;
            short8_t a0f = *(const short8_t*)(al + r0 * KT + ((ch ^ (r0 & 7)) << 3));
            short8_t a1f = *(const short8_t*)(al + r1 * KT + ((ch ^ (r1 & 7)) << 3));
            acc00 = __builtin_amdgcn_mfma_f32_16x16x32_bf16(a0f, b0f, acc00, 0, 0, 0);
            acc01 = __builtin_amdgcn_mfma_f32_16x16x32_bf16(a0f, b1f, acc01, 0, 0, 0);
            acc10 = __builtin_amdgcn_mfma_f32_16x16x32_bf16(a1f, b0f, acc10, 0, 0, 0);
            acc11 = __builtin_amdgcn_mfma_f32_16x16x32_bf16(a1f, b1f, acc11, 0, 0, 0);
        }
    };

    // prologue
    issue(0, paA, pwA);
    stage(paA, pwA, Al0, Wl0);
    issue(1, paB, pwB);
    __syncthreads();                       // publish buf0

    for (int t = 0; t < nt; t += 2) {
        if (t + 2 < nt) issue(t + 2, paA, pwA);
        stage(paB, pwB, Al1, Wl1);         // tile t+1 -> buf1
        compute(Al0, Wl0);                 // tile t
        __syncthreads();                   // publish buf1
        if (t + 3 < nt) issue(t + 3, paB, pwB);
        if (t + 2 < nt) stage(paA, pwA, Al0, Wl0);
        compute(Al1, Wl1);                 // tile t+1
        __syncthreads();                   // publish buf0
    }

    // epilogue: D mapping col=lane&15, row=4*(lane>>4)+reg  [m89/m91]
    float* zrow = d.p[pi].Z + (size_t)kb * 256 * N;
#pragma unroll
    for (int r = 0; r < 4; ++r) {
        int ma = m0 + lg * 4 + r;
        int mb = ma + 16;
        zrow[(size_t)ma * N + n0 + lr]      = acc00[r];
        zrow[(size_t)ma * N + n0 + 16 + lr] = acc01[r];
        zrow[(size_t)mb * N + n0 + lr]      = acc10[r];
        zrow[(size_t)mb * N + n0 + 16 + lr] = acc11[r];
    }
}

// ---------------------------------------------------------------------------
// Gates: z = sum(pz1[0..n1)) + sum(pz2[0..n2)) + bias -> h,c fp32 + h bf16
// Partial stride = 1048576 floats (one [256][4096] slot).
// ---------------------------------------------------------------------------
__global__ __launch_bounds__(256)
void lstm_gates(const float* __restrict__ pz1, int n1,
                const float* __restrict__ pz2, int n2,
                const float* __restrict__ bias, const float* __restrict__ c_old,
                float* __restrict__ h_out, float* __restrict__ c_out,
                unsigned short* __restrict__ h_bf)
{
    int t = blockIdx.x * 256 + threadIdx.x;   // 65536 threads, 4 elems each
    int b = t >> 8;
    int n = (t & 255) << 2;
    f32x4 iv = *(const f32x4*)(bias + n);
    f32x4 fv = *(const f32x4*)(bias + 1024 + n);
    f32x4 gv = *(const f32x4*)(bias + 2048 + n);
    f32x4 ov = *(const f32x4*)(bias + 3072 + n);
    for (int i = 0; i < n1; ++i) {
        const float* z = pz1 + (size_t)i * 1048576 + (size_t)b * 4096;
        iv += *(const f32x4*)(z + n);
        fv += *(const f32x4*)(z + 1024 + n);
        gv += *(const f32x4*)(z + 2048 + n);
        ov += *(const f32x4*)(z + 3072 + n);
    }
    for (int i = 0; i < n2; ++i) {
        const float* z = pz2 + (size_t)i * 1048576 + (size_t)b * 4096;
        iv += *(const f32x4*)(z + n);
        fv += *(const f32x4*)(z + 1024 + n);
        gv += *(const f32x4*)(z + 2048 + n);
        ov += *(const f32x4*)(z + 3072 + n);
    }
    f32x4 cv = *(const f32x4*)(c_old + (size_t)b * 1024 + n);

    f32x4 hn, cn;
    ushort4_t hb;
#pragma unroll
    for (int j = 0; j < 4; ++j) {
        float ii = 1.f / (1.f + __expf(-iv[j]));
        float ff = 1.f / (1.f + __expf(-fv[j]));
        float gg = tanhf(gv[j]);
        float oo = 1.f / (1.f + __expf(-ov[j]));
        float c2 = ff * cv[j] + ii * gg;
        cn[j] = c2;
        float h2 = oo * tanhf(c2);
        hn[j] = h2;
        hb[j] = f2bf(h2);
    }
    *(f32x4*)(c_out + (size_t)b * 1024 + n) = cn;
    *(f32x4*)(h_out + (size_t)b * 1024 + n) = hn;
    *(ushort4_t*)(h_bf + (size_t)b * 1024 + n) = hb;
}

// ---------------------------------------------------------------------------
// logits = sum_kb zp[kb] + bp   (proj partial reduce), partial stride 131072
// ---------------------------------------------------------------------------
__global__ __launch_bounds__(256)
void finalize_proj(const float* __restrict__ zp, int nsplit,
                   const float* __restrict__ bp, float* __restrict__ logits)
{
    int t = blockIdx.x * 256 + threadIdx.x;   // 32768 threads x 4 elems
    int i = t * 4;
    f32x4 v = *(const f32x4*)(bp + (i & 511));
    for (int kb = 0; kb < nsplit; ++kb)
        v += *(const f32x4*)(zp + (size_t)kb * 131072 + i);
    *(f32x4*)(logits + i) = v;
}

// ---------------------------------------------------------------------------
// Pack fp32 -> bf16 for x, h0, h1, h2
// ---------------------------------------------------------------------------
__global__ __launch_bounds__(256)
void pack_bf16(const float* __restrict__ x,  const float* __restrict__ h0,
               const float* __restrict__ h1, const float* __restrict__ h2,
               unsigned short* __restrict__ xb,  unsigned short* __restrict__ h0b,
               unsigned short* __restrict__ h1b, unsigned short* __restrict__ h2b)
{
    int t = blockIdx.x * 256 + threadIdx.x;
    const float* src; unsigned short* dst; int off;
    if (t < 32768)       { src = x;  dst = xb;  off = t; }
    else if (t < 98304)  { src = h0; dst = h0b; off = t - 32768; }
    else if (t < 163840) { src = h1; dst = h1b; off = t - 98304; }
    else                 { src = h2; dst = h2b; off = t - 163840; }
    f32x4 v = *(const f32x4*)(src + (size_t)off * 4);
    ushort4_t o;
#pragma unroll
    for (int j = 0; j < 4; ++j) o[j] = f2bf(v[j]);
    *(ushort4_t*)(dst + (size_t)off * 4) = o;
}

// ---------------------------------------------------------------------------
extern "C" void kernel_launch(void* const* d_in, const int* in_sizes, int n_in,
                              void* d_out, int out_size, void* d_ws, size_t ws_size,
                              hipStream_t stream)
{
    const float* x  = (const float*)d_in[0];
    const float* h0 = (const float*)d_in[1];
    const float* c0 = (const float*)d_in[2];
    const float* h1 = (const float*)d_in[3];
    const float* c1 = (const float*)d_in[4];
    const float* h2 = (const float*)d_in[5];
    const float* c2 = (const float*)d_in[6];
    const float* W0 = (const float*)d_in[7];
    const float* U0 = (const float*)d_in[8];
    const float* b0 = (const float*)d_in[9];
    const float* W1 = (const float*)d_in[10];
    const float* U1 = (const float*)d_in[11];
    const float* b1 = (const float*)d_in[12];
    const float* W2 = (const float*)d_in[13];
    const float* U2 = (const float*)d_in[14];
    const float* b2 = (const float*)d_in[15];
    const float* Wp = (const float*)d_in[16];
    const float* bp = (const float*)d_in[17];

    float* out    = (float*)d_out;
    float* logits = out;                    // [256,512]
    float* h0n = out + 131072;              // [256,1024] each below
    float* c0n = h0n + 262144;
    float* h1n = c0n + 262144;
    float* c1n = h1n + 262144;
    float* h2n = c1n + 262144;
    float* c2n = h2n + 262144;

    const size_t SLOT = 1048576;            // floats per [256][4096] slot
    const size_t bf_bytes = 262144ull + 6ull * 524288ull;            // 3.25 MB
    const size_t need6 = 6ull * 4194304ull + bf_bytes;
    const size_t need4 = 4ull * 4194304ull + bf_bytes;
    const int nslots = (ws_size >= need6) ? 6 : (ws_size >= need4) ? 4 : 2;

    float* S = (float*)d_ws;
    auto S_at = [&](int i) { return S + (size_t)i * SLOT; };
    unsigned short* bufs = (unsigned short*)(S + (size_t)nslots * SLOT);
    unsigned short* xb   = bufs;
    unsigned short* h0b  = bufs + 131072;
    unsigned short* h1b  = h0b + 262144;
    unsigned short* h2b  = h1b + 262144;
    unsigned short* h0nb = h2b + 262144;
    unsigned short* h1nb = h0nb + 262144;
    unsigned short* h2nb = h1nb + 262144;

    pack_bf16<<<896, 256, 0, stream>>>(x, h0, h1, h2, xb, h0b, h1b, h2b);

    if (nslots >= 4) {
        float* Su1 = S_at(nslots == 6 ? 4 : 2);
        float* Su2 = S_at(nslots == 6 ? 5 : 3);

        // mega: all products available at t=0 (56 MB of weights, 512 blocks)
        GemmDesc mega;
        mega.p[0] = { xb,  W0, S_at(0), 512,  0, 0   };
        mega.p[1] = { h0b, U0, S_at(1), 1024, 0, 128 };
        mega.p[2] = { h1b, U1, Su1,     1024, 0, 256 };
        mega.p[3] = { h2b, U2, Su2,     1024, 0, 384 };
        mega.np = 4; mega.N = 4096;
        gemm_multi<<<512, 512, 0, stream>>>(mega);
        lstm_gates<<<256, 256, 0, stream>>>(S_at(0), 2, nullptr, 0, b0, c0,
                                            h0n, c0n, h0nb);

        const int lgsG = (nslots == 6) ? 2 : 1;   // G1/G2 K-split
        GemmDesc g1;
        g1.p[0] = { h0nb, W1, S_at(0), 1024, lgsG, 0 };
        g1.p[1] = g1.p[2] = g1.p[3] = g1.p[0];
        g1.np = 1; g1.N = 4096;
        gemm_multi<<<128 << lgsG, 512, 0, stream>>>(g1);
        lstm_gates<<<256, 256, 0, stream>>>(S_at(0), 1 << lgsG, Su1, 1, b1, c1,
                                            h1n, c1n, h1nb);

        GemmDesc g2;
        g2.p[0] = { h1nb, W2, S_at(0), 1024, lgsG, 0 };
        g2.p[1] = g2.p[2] = g2.p[3] = g2.p[0];
        g2.np = 1; g2.N = 4096;
        gemm_multi<<<128 << lgsG, 512, 0, stream>>>(g2);
        lstm_gates<<<256, 256, 0, stream>>>(S_at(0), 1 << lgsG, Su2, 1, b2, c2,
                                            h2n, c2n, h2nb);

        float* Sp = (nslots == 6) ? S_at(4) : S_at(2);
        GemmDesc gp;
        gp.p[0] = { h2nb, Wp, Sp, 1024, 2, 0 };
        gp.p[1] = gp.p[2] = gp.p[3] = gp.p[0];
        gp.np = 1; gp.N = 512;
        gemm_multi<<<64, 512, 0, stream>>>(gp);
        finalize_proj<<<128, 256, 0, stream>>>(Sp, 4, bp, logits);
    } else {
        // 2-slot fallback: merge each layer's W-product with the next U-product
        GemmDesc m1;
        m1.p[0] = { xb,  W0, S_at(0), 512,  0, 0   };
        m1.p[1] = { h0b, U0, S_at(1), 1024, 0, 128 };
        m1.p[2] = m1.p[3] = m1.p[1];
        m1.np = 2; m1.N = 4096;
        gemm_multi<<<256, 512, 0, stream>>>(m1);
        lstm_gates<<<256, 256, 0, stream>>>(S_at(0), 2, nullptr, 0, b0, c0,
                                            h0n, c0n, h0nb);
        GemmDesc m2;
        m2.p[0] = { h0nb, W1, S_at(0), 1024, 0, 0   };
        m2.p[1] = { h1b,  U1, S_at(1), 1024, 0, 128 };
        m2.p[2] = m2.p[3] = m2.p[1];
        m2.np = 2; m2.N = 4096;
        gemm_multi<<<256, 512, 0, stream>>>(m2);
        lstm_gates<<<256, 256, 0, stream>>>(S_at(0), 2, nullptr, 0, b1, c1,
                                            h1n, c1n, h1nb);
        GemmDesc m3;
        m3.p[0] = { h1nb, W2, S_at(0), 1024, 0, 0   };
        m3.p[1] = { h2b,  U2, S_at(1), 1024, 0, 128 };
        m3.p[2] = m3.p[3] = m3.p[1];
        m3.np = 2; m3.N = 4096;
        gemm_multi<<<256, 512, 0, stream>>>(m3);
        lstm_gates<<<256, 256, 0, stream>>>(S_at(0), 2, nullptr, 0, b2, c2,
                                            h2n, c2n, h2nb);
        GemmDesc gp;
        gp.p[0] = { h2nb, Wp, S_at(1), 1024, 2, 0 };
        gp.p[1] = gp.p[2] = gp.p[3] = gp.p[0];
        gp.np = 1; gp.N = 512;
        gemm_multi<<<64, 512, 0, stream>>>(gp);
        finalize_proj<<<128, 256, 0, stream>>>(S_at(1), 4, bp, logits);
    }
}